// Round 2
// baseline (596.298 us; speedup 1.0000x reference)
//
#include <hip/hip_runtime.h>
#include <stdint.h>

// dynamic_gcn: B=16, C=32, N=128, T=12, C_OUT=64, fp32 in/out (bf16-level tolerance).
// x1[b,i,k,l] = sum_j x[b,i,j,l]*A[b,i,j,k,l]; x2 = same with x1 in place of x;
// out[b,o,k,l] = sum_c W[o,c]*h[b,c,k,l] + bias[o], h = concat(x1,x2) on c.

#define NN 128
#define TT 12
#define KL 1536            // N*T fp32 per j-row
#define KLV 384            // KL/4  (float4)
#define CHUNK4 (NN * KLV)  // float4 per (b,i) chunk of A = 49152 (768 KB)

// Persistent grid: 256 blocks (≈1/CU), each handles chunks bx and bx+256.
// Pass 1 streams the 768 KB chunk from HBM computing x1 (fp32 acc in regs,
// x staged in LDS); pass 2 immediately re-streams the same chunk — with only
// ~256 chunks co-resident (192 MB < 256 MB Infinity Cache) the re-read is
// L3-served, so A costs ~1 HBM pass total.
__global__ __launch_bounds__(384) void gcn_prop_kernel(
    const float4* __restrict__ A4,
    const float4* __restrict__ x4,
    float4* __restrict__ h4)
{
    __shared__ float4 xs[KLV];   // x[b,i,:,:]  layout [j*3 + l4]
    __shared__ float4 x1s[KLV];  // x1 same layout
    const int t = threadIdx.x;       // 0..383 : k = t/3, l4 = t%3 (l = 4*l4)
    const int la4 = t % 3;

    for (int rep = 0; rep < 2; ++rep) {
        const int cid = blockIdx.x + rep * 256;   // 0..511 = b*32 + i
        const int bb = cid >> 5;
        const int ii = cid & 31;
        const float4* Ab = A4 + (size_t)cid * CHUNK4 + t;

        xs[t] = x4[cid * KLV + t];
        __syncthreads();

        float4 acc = make_float4(0.f, 0.f, 0.f, 0.f);
        #pragma unroll 8
        for (int j = 0; j < NN; ++j) {
            float4 a  = Ab[j * KLV];       // contiguous 1 KB per wave per j
            float4 xv = xs[j * 3 + la4];   // 3 distinct addrs/wave: conflict-free
            acc.x = fmaf(xv.x, a.x, acc.x);
            acc.y = fmaf(xv.y, a.y, acc.y);
            acc.z = fmaf(xv.z, a.z, acc.z);
            acc.w = fmaf(xv.w, a.w, acc.w);
        }
        x1s[t] = acc;
        h4[(size_t)(bb * 64 + ii) * KLV + t] = acc;   // h channel i = x1
        __syncthreads();

        float4 acc2 = make_float4(0.f, 0.f, 0.f, 0.f);
        #pragma unroll 8
        for (int j = 0; j < NN; ++j) {
            float4 a  = Ab[j * KLV];       // second pass: L3-resident
            float4 xv = x1s[j * 3 + la4];
            acc2.x = fmaf(xv.x, a.x, acc2.x);
            acc2.y = fmaf(xv.y, a.y, acc2.y);
            acc2.z = fmaf(xv.z, a.z, acc2.z);
            acc2.w = fmaf(xv.w, a.w, acc2.w);
        }
        h4[(size_t)(bb * 64 + 32 + ii) * KLV + t] = acc2; // channel 32+i = x2
        __syncthreads();  // protect xs/x1s before next rep rewrites them
    }
}

// 1x1 conv over channels: block = (b, o-group of 8). Thread t owns kl=4t..4t+3.
// 8 outputs per h-read → L2 traffic /8 vs per-(b,o) blocking.
__global__ __launch_bounds__(384) void mix_kernel(
    const float4* __restrict__ h4,
    const float* __restrict__ W,     // [64][64]
    const float* __restrict__ bias,  // [64]
    float4* __restrict__ out4)
{
    __shared__ float wsm[8][64];
    __shared__ float bsm[8];
    const int t = threadIdx.x;
    const int b  = blockIdx.x >> 3;
    const int o0 = (blockIdx.x & 7) * 8;
    if (t < 512) {
        const int o = t >> 6, c = t & 63;
        if (t < 384) wsm[o][c] = W[(o0 + o) * 64 + c];
    }
    // cover rows 6,7 (t=384..511 don't exist with 384 threads)
    if (t < 128) {
        const int o = 6 + (t >> 6), c = t & 63;
        wsm[o][c] = W[(o0 + o) * 64 + c];
    }
    if (t < 8) bsm[t] = bias[o0 + t];
    __syncthreads();

    float4 acc[8];
    #pragma unroll
    for (int o = 0; o < 8; ++o) {
        const float bv = bsm[o];
        acc[o] = make_float4(bv, bv, bv, bv);
    }
    const float4* hb = h4 + (size_t)b * 64 * KLV + t;
    for (int c = 0; c < 64; ++c) {
        float4 hv = hb[(size_t)c * KLV];     // coalesced across t; L2-resident
        #pragma unroll
        for (int o = 0; o < 8; ++o) {
            const float w = wsm[o][c];       // broadcast: conflict-free
            acc[o].x = fmaf(w, hv.x, acc[o].x);
            acc[o].y = fmaf(w, hv.y, acc[o].y);
            acc[o].z = fmaf(w, hv.z, acc[o].z);
            acc[o].w = fmaf(w, hv.w, acc[o].w);
        }
    }
    #pragma unroll
    for (int o = 0; o < 8; ++o)
        out4[(size_t)(b * 64 + o0 + o) * KLV + t] = acc[o];
}

extern "C" void kernel_launch(void* const* d_in, const int* in_sizes, int n_in,
                              void* d_out, int out_size, void* d_ws, size_t ws_size,
                              hipStream_t stream) {
    const float4* x4 = (const float4*)d_in[0];   // x  [16,32,128,12] fp32
    const float4* A4 = (const float4*)d_in[1];   // A  [16,32,128,128,12] fp32
    const float*  W  = (const float*)d_in[2];    // W  [64,64] fp32
    const float*  bs = (const float*)d_in[3];    // b  [64] fp32
    float4* h4   = (float4*)d_ws;                // h  [16,64,128,12] fp32 = 6 MB
    float4* out4 = (float4*)d_out;               // out[16,64,128,12] fp32

    gcn_prop_kernel<<<dim3(256), dim3(384), 0, stream>>>(A4, x4, h4);
    mix_kernel<<<dim3(128), dim3(384), 0, stream>>>(h4, W, bs, out4);
}

// Round 3
// 592.660 us; speedup vs baseline: 1.0061x; 1.0061x over previous
//
#include <hip/hip_runtime.h>
#include <stdint.h>

// dynamic_gcn: B=16, C=32, N=128, T=12, C_OUT=64, fp32 in/out.
// x1[b,i,k,l] = sum_j x[b,i,j,l]*A[b,i,j,k,l]; x2 = same with x1 in place of x;
// out[b,o,k,l] = sum_c W[o,c]*h[b,c,k,l] + bias[o], h = concat(x1,x2) on c.

#define NN 128
#define TT 12
#define KL 1536            // N*T fp32 per j-row
#define KLV 384            // KL/4  (float4)
#define CHUNK4 (NN * KLV)  // float4 per (b,i) chunk of A = 49152 (768 KB)

// Persistent grid: 256 blocks (1/CU) x 768 threads (12 waves/CU), each block
// handles chunks bx and bx+256. The 768 threads split the j-range in half
// (half 0: j 0..63, half 1: j 64..127), each computing a partial x1/x2 for
// its (k,l) slot; partials combine through LDS. Doubles memory parallelism
// vs the 384-thread version while keeping the co-resident chunk set at
// 256 x 768 KB = 192 MB < 256 MB Infinity Cache, so the pass-2 re-read of A
// is L3-served. Pass 2 walks j in reverse per half: hottest lines first.
__global__ __launch_bounds__(768) void gcn_prop_kernel(
    const float4* __restrict__ A4,
    const float4* __restrict__ x4,
    float4* __restrict__ h4)
{
    __shared__ float4 xs[KLV];    // x[b,i,:,:]   layout [j*3 + l4]   (6 KB)
    __shared__ float4 x1s[KLV];   // x1 combined  same layout         (6 KB)
    __shared__ float4 psum[768];  // per-half partial sums            (12 KB)
    const int t = threadIdx.x;        // 0..767
    const int half = (t >= KLV);      // j-range half
    const int th = t - half * KLV;    // 0..383 : k = th/3, l4 = th%3
    const int la4 = th % 3;
    const int j0 = half * 64;

    for (int rep = 0; rep < 2; ++rep) {
        const int cid = blockIdx.x + rep * 256;   // 0..511 = b*32 + i
        const int bb = cid >> 5;
        const int ii = cid & 31;
        const float4* Ab = A4 + (size_t)cid * CHUNK4 + th;

        if (t < KLV) xs[t] = x4[cid * KLV + t];
        __syncthreads();

        // ---- pass 1: x1 partial over this half's j range ----
        float4 acc = make_float4(0.f, 0.f, 0.f, 0.f);
        #pragma unroll 8
        for (int jj = 0; jj < 64; ++jj) {
            const int j = j0 + jj;
            float4 a  = Ab[j * KLV];       // 1 KB contiguous per wave per j
            float4 xv = xs[j * 3 + la4];   // 3 distinct addrs/wave: broadcast
            acc.x = fmaf(xv.x, a.x, acc.x);
            acc.y = fmaf(xv.y, a.y, acc.y);
            acc.z = fmaf(xv.z, a.z, acc.z);
            acc.w = fmaf(xv.w, a.w, acc.w);
        }
        psum[t] = acc;
        __syncthreads();
        if (t < KLV) {
            float4 p0 = psum[t], p1 = psum[t + KLV];
            float4 tot = make_float4(p0.x + p1.x, p0.y + p1.y,
                                     p0.z + p1.z, p0.w + p1.w);
            x1s[t] = tot;
            h4[(size_t)(bb * 64 + ii) * KLV + t] = tot;       // h ch i = x1
        }
        __syncthreads();

        // ---- pass 2: x2 partial, reverse j (hot L3 tail first) ----
        float4 acc2 = make_float4(0.f, 0.f, 0.f, 0.f);
        #pragma unroll 8
        for (int jj = 0; jj < 64; ++jj) {
            const int j = j0 + 63 - jj;
            float4 a  = Ab[j * KLV];       // L3-resident re-read
            float4 xv = x1s[j * 3 + la4];
            acc2.x = fmaf(xv.x, a.x, acc2.x);
            acc2.y = fmaf(xv.y, a.y, acc2.y);
            acc2.z = fmaf(xv.z, a.z, acc2.z);
            acc2.w = fmaf(xv.w, a.w, acc2.w);
        }
        psum[t] = acc2;
        __syncthreads();
        if (t < KLV) {
            float4 p0 = psum[t], p1 = psum[t + KLV];
            float4 tot = make_float4(p0.x + p1.x, p0.y + p1.y,
                                     p0.z + p1.z, p0.w + p1.w);
            h4[(size_t)(bb * 64 + 32 + ii) * KLV + t] = tot;  // h ch 32+i = x2
        }
        __syncthreads();  // protect xs/x1s before next rep rewrites them
    }
}

// 1x1 conv over channels: block = (b, o-group of 8). Thread t owns kl=4t..4t+3.
__global__ __launch_bounds__(384) void mix_kernel(
    const float4* __restrict__ h4,
    const float* __restrict__ W,     // [64][64]
    const float* __restrict__ bias,  // [64]
    float4* __restrict__ out4)
{
    __shared__ float wsm[8][64];
    __shared__ float bsm[8];
    const int t = threadIdx.x;
    const int b  = blockIdx.x >> 3;
    const int o0 = (blockIdx.x & 7) * 8;
    {
        const int o = t >> 6, c = t & 63;
        if (t < 384) wsm[o][c] = W[(o0 + o) * 64 + c];        // rows 0..5
    }
    if (t < 128) {
        const int o = 6 + (t >> 6), c = t & 63;
        wsm[o][c] = W[(o0 + o) * 64 + c];                     // rows 6,7
    }
    if (t < 8) bsm[t] = bias[o0 + t];
    __syncthreads();

    float4 acc[8];
    #pragma unroll
    for (int o = 0; o < 8; ++o) {
        const float bv = bsm[o];
        acc[o] = make_float4(bv, bv, bv, bv);
    }
    const float4* hb = h4 + (size_t)b * 64 * KLV + t;
    for (int c = 0; c < 64; ++c) {
        float4 hv = hb[(size_t)c * KLV];     // coalesced across t; L2-resident
        #pragma unroll
        for (int o = 0; o < 8; ++o) {
            const float w = wsm[o][c];       // broadcast: conflict-free
            acc[o].x = fmaf(w, hv.x, acc[o].x);
            acc[o].y = fmaf(w, hv.y, acc[o].y);
            acc[o].z = fmaf(w, hv.z, acc[o].z);
            acc[o].w = fmaf(w, hv.w, acc[o].w);
        }
    }
    #pragma unroll
    for (int o = 0; o < 8; ++o)
        out4[(size_t)(b * 64 + o0 + o) * KLV + t] = acc[o];
}

extern "C" void kernel_launch(void* const* d_in, const int* in_sizes, int n_in,
                              void* d_out, int out_size, void* d_ws, size_t ws_size,
                              hipStream_t stream) {
    const float4* x4 = (const float4*)d_in[0];   // x  [16,32,128,12] fp32
    const float4* A4 = (const float4*)d_in[1];   // A  [16,32,128,128,12] fp32
    const float*  W  = (const float*)d_in[2];    // W  [64,64] fp32
    const float*  bs = (const float*)d_in[3];    // b  [64] fp32
    float4* h4   = (float4*)d_ws;                // h  [16,64,128,12] fp32 = 6 MB
    float4* out4 = (float4*)d_out;               // out[16,64,128,12] fp32

    gcn_prop_kernel<<<dim3(256), dim3(768), 0, stream>>>(A4, x4, h4);
    mix_kernel<<<dim3(128), dim3(384), 0, stream>>>(h4, W, bs, out4);
}